// Round 3
// baseline (639.347 us; speedup 1.0000x reference)
//
#include <hip/hip_runtime.h>
#include <hip/hip_bf16.h>

#define N_NODES 8192
#define D_IN    512
#define H       256
#define D_OUT   16
#define K_CL    16
#define MAXN    96

// flat output element offsets (dtype-agnostic): output | Z_1 | Z_0 | score
#define OUT_OFF 0
#define Z1_OFF  131072
#define Z0_OFF  262144
#define SC_OFF  2359296

typedef unsigned int   u32;
typedef unsigned short u16;
typedef short s16x8 __attribute__((ext_vector_type(8)));   // bf16 MFMA A/B frag (guide-verified type)
typedef float f32x4 __attribute__((ext_vector_type(4)));   // MFMA C/D frag

__device__ __forceinline__ float load_in(const void* p, int bf, size_t idx) {
    if (bf) { u32 w = ((const u16*)p)[idx]; return __uint_as_float(w << 16); }
    return ((const float*)p)[idx];
}
__device__ __forceinline__ void store_out(void* p, int bf, size_t idx, float v) {
    if (bf) ((__hip_bfloat16*)p)[idx] = __float2bfloat16(v);
    else    ((float*)p)[idx] = v;
}

// bf16 {0,1} arrays contain u32 word 0x00003F80 (pair (1.0, 0.0));
// fp32 {0.0f,1.0f} arrays contain only 0x00000000 / 0x3F800000.
__global__ void k_detect(const u32* __restrict__ adjw, int* __restrict__ flag) {
    int t = blockIdx.x * 256 + threadIdx.x;
    int hit = 0;
    #pragma unroll 4
    for (int i = 0; i < 64; i++)
        if (adjw[(size_t)t + (size_t)i * 16384] == 0x00003F80u) hit = 1;
    if (hit) atomicOr(flag, 1);
}

// convert a / C_a / W_gcn to f32; transpose W -> Wt (bf16, [H][D_IN]) for MFMA B-frags
__global__ void k_prep(const void* av, const void* C_a, const void* Wgcn, const void* W,
                       const int* __restrict__ flag,
                       float* a_f, float* Ca_f, float* Wg_f, u16* Wt) {
    int bf = *flag;
    int i = blockIdx.x * 256 + threadIdx.x;
    if (i < 512)        a_f[i]         = load_in(av,   bf, i);
    else if (i < 4608)  Ca_f[i - 512]  = load_in(C_a,  bf, i - 512);
    else if (i < 8704)  Wg_f[i - 4608] = load_in(Wgcn, bf, i - 4608);
    else if (i < 139776 && bf) {
        int j = i - 8704;
        int nn = j >> 9, kk = j & 511;           // Wt[nn][kk] = W[kk][nn]
        Wt[j] = ((const u16*)W)[(size_t)kk * H + nn];
    }
}

// Wh = x @ W.  bf16: MFMA 16x16x32, direct-from-global frags. fp32: VALU fallback.
__global__ __launch_bounds__(256) void k_gemm_wh(
    const void* __restrict__ xraw, const void* __restrict__ wraw,
    const u16* __restrict__ Wt, const int* __restrict__ flag,
    float* __restrict__ Wh)
{
    int bf = *flag;
    int tid = threadIdx.x, wave = tid >> 6, lane = tid & 63;
    int w = blockIdx.x * 4 + wave;           // 8192 tiles: 512 mt x 16 nt
    int mt = w >> 4, nt = w & 15;
    int m0 = mt * 16, n0 = nt * 16;
    int quad = lane >> 4, lr = lane & 15;

    if (bf) {
        const u16* xa = (const u16*)xraw + (size_t)(m0 + lr) * D_IN + quad * 8;
        const u16* bb = Wt + (size_t)(n0 + lr) * D_IN + quad * 8;
        f32x4 acc = {0.f, 0.f, 0.f, 0.f};
        #pragma unroll
        for (int k0 = 0; k0 < D_IN; k0 += 32) {
            s16x8 a = *(const s16x8*)(xa + k0);   // A[m=lr][k0+quad*8 ..+8)
            s16x8 b = *(const s16x8*)(bb + k0);   // B[k0+quad*8 ..+8)[n=lr]
            acc = __builtin_amdgcn_mfma_f32_16x16x32_bf16(a, b, acc, 0, 0, 0);
        }
        float* cp = Wh + (size_t)(m0 + quad * 4) * H + n0 + lr;  // row=quad*4+i, col=lr
        #pragma unroll
        for (int i = 0; i < 4; i++) cp[(size_t)i * H] = acc[i];
    } else {
        const float* xa = (const float*)xraw + (size_t)(m0 + lr) * D_IN;
        const float* wb = (const float*)wraw;
        float c0 = 0.f, c1 = 0.f, c2 = 0.f, c3 = 0.f;
        for (int k = 0; k < D_IN; k++) {
            float a = xa[k];
            const float* wr = wb + (size_t)k * H + n0 + quad * 4;
            c0 += a * wr[0]; c1 += a * wr[1]; c2 += a * wr[2]; c3 += a * wr[3];
        }
        float* cp = Wh + (size_t)(m0 + lr) * H + n0 + quad * 4;
        cp[0] = c0; cp[1] = c1; cp[2] = c2; cp[3] = c3;
    }
}

__global__ __launch_bounds__(256) void k_wh12(
    const float* __restrict__ Wh, const float* __restrict__ a_f,
    float* __restrict__ Wh1, float* __restrict__ Wh2)
{
    int tid = threadIdx.x;
    int wave = tid >> 6, lane = tid & 63;
    int n = blockIdx.x * 4 + wave;
    float4 v  = *(const float4*)(Wh + (size_t)n * H + lane * 4);
    float4 a1 = *(const float4*)(a_f + lane * 4);
    float4 a2 = *(const float4*)(a_f + H + lane * 4);
    float s1 = v.x*a1.x + v.y*a1.y + v.z*a1.z + v.w*a1.w;
    float s2 = v.x*a2.x + v.y*a2.y + v.z*a2.z + v.w*a2.w;
    #pragma unroll
    for (int off = 32; off; off >>= 1) {
        s1 += __shfl_xor(s1, off);
        s2 += __shfl_xor(s2, off);
    }
    if (lane == 0) { Wh1[n] = s1; Wh2[n] = s2; }
}

__global__ __launch_bounds__(256) void k_gat_row(
    const void* __restrict__ adjraw, const int* __restrict__ flag,
    const float* __restrict__ Wh,
    const float* __restrict__ Wh1, const float* __restrict__ Wh2,
    const float* __restrict__ Ca_f, const float* __restrict__ Wg_f,
    float* __restrict__ Gf,
    int* __restrict__ nbr_cnt, u16* __restrict__ nbr_idx,
    void* __restrict__ dout)
{
    const int n = blockIdx.x;
    const int tid = threadIdx.x;
    const int wave = tid >> 6, lane = tid & 63;
    const int bf = *flag;
    __shared__ int   s_cnt;
    __shared__ int   s_idx[MAXN];
    __shared__ float s_att[MAXN];
    __shared__ float s_z[H];
    __shared__ float s_g[H];
    __shared__ float s_red[256];
    __shared__ float s_sc[16];

    if (tid == 0) s_cnt = 0;
    __syncthreads();                                               // B1

    // -- scan adj row, collect neighbor indices --
    if (bf) {
        const u16* arow = (const u16*)adjraw + (size_t)n * N_NODES;
        #pragma unroll
        for (int it = 0; it < 4; it++) {
            int base = it * 2048 + tid * 8;
            uint4 raw = *(const uint4*)(arow + base);
            u32 rw[4] = {raw.x, raw.y, raw.z, raw.w};
            #pragma unroll
            for (int q = 0; q < 4; q++) {
                #pragma unroll
                for (int hh = 0; hh < 2; hh++) {
                    u32 u = (rw[q] >> (16 * hh)) & 0xFFFFu;
                    if (__uint_as_float(u << 16) > 0.f) {
                        int p = atomicAdd(&s_cnt, 1);
                        if (p < MAXN) s_idx[p] = base + q * 2 + hh;
                    }
                }
            }
        }
    } else {
        const float* arow = (const float*)adjraw + (size_t)n * N_NODES;
        #pragma unroll
        for (int it = 0; it < 8; it++) {
            int base = it * 1024 + tid * 4;
            float4 v = *(const float4*)(arow + base);
            float vv[4] = {v.x, v.y, v.z, v.w};
            #pragma unroll
            for (int q = 0; q < 4; q++) {
                if (vv[q] > 0.f) {
                    int p = atomicAdd(&s_cnt, 1);
                    if (p < MAXN) s_idx[p] = base + q;
                }
            }
        }
    }
    __syncthreads();                                               // B2
    const int cnt = min(s_cnt, MAXN);
    if (tid == 0) nbr_cnt[n] = cnt;
    if (tid < cnt) nbr_idx[(size_t)n * MAXN + tid] = (u16)s_idx[tid];

    // -- softmax over neighbors, single wave (cnt <= 96), shuffle butterflies --
    if (wave == 0) {
        int t1 = lane, t2 = 64 + lane;
        float whn = Wh1[n];
        float e1 = -3e38f, e2 = -3e38f;
        if (t1 < cnt) { float v = whn + Wh2[s_idx[t1]]; e1 = v > 0.f ? v : 0.2f * v; }
        if (t2 < cnt) { float v = whn + Wh2[s_idx[t2]]; e2 = v > 0.f ? v : 0.2f * v; }
        float m = fmaxf(e1, e2);
        #pragma unroll
        for (int off = 32; off; off >>= 1) m = fmaxf(m, __shfl_xor(m, off));
        float x1 = (t1 < cnt) ? expf(e1 - m) : 0.f;
        float x2 = (t2 < cnt) ? expf(e2 - m) : 0.f;
        float s = x1 + x2;
        #pragma unroll
        for (int off = 32; off; off >>= 1) s += __shfl_xor(s, off);
        float inv = 1.f / s;
        if (t1 < cnt) s_att[t1] = x1 * inv;
        if (t2 < cnt) s_att[t2] = x2 * inv;
    }
    __syncthreads();                                               // B3

    // -- Z0[n][h] = sum_j att_j * Wh[j][h];  h = tid --
    float acc = 0.f;
    for (int t = 0; t < cnt; t++)
        acc += s_att[t] * Wh[(size_t)s_idx[t] * H + tid];
    s_z[tid] = acc;
    store_out(dout, bf, (size_t)Z0_OFF + (size_t)n * H + tid, acc);
    s_g[tid] = acc > 0.f ? acc : expf(acc) - 1.f;
    __syncthreads();                                               // B4

    // -- score partials --
    {
        int k = tid & 15, hb = (tid >> 4) * 16;
        float p = 0.f;
        #pragma unroll
        for (int i = 0; i < 16; i++) {
            float d = s_z[hb + i] - Ca_f[(size_t)k * H + hb + i];
            p += d * d;
        }
        s_red[tid] = p;
    }
    __syncthreads();                                               // B5
    if (tid < 16) {
        float d2 = 0.f;
        #pragma unroll
        for (int q = 0; q < 16; q++) d2 += s_red[q * 16 + tid];
        s_sc[tid] = expf(-sqrtf(d2)) + 1e-10f;
    }
    __syncthreads();                                               // B6
    // -- score store + G partials (s_red reuse safe: old readers done at B6) --
    if (tid < 16) {
        float tot = 0.f;
        #pragma unroll
        for (int q = 0; q < 16; q++) tot += s_sc[q];
        store_out(dout, bf, (size_t)SC_OFF + (size_t)n * K_CL + tid, s_sc[tid] / tot);
    }
    {
        int o = tid & 15, hb = (tid >> 4) * 16;
        float p = 0.f;
        #pragma unroll
        for (int i = 0; i < 16; i++)
            p += s_g[hb + i] * Wg_f[(size_t)(hb + i) * D_OUT + o];
        s_red[tid] = p;
    }
    __syncthreads();                                               // B7
    if (tid < 16) {
        float g2 = 0.f;
        #pragma unroll
        for (int q = 0; q < 16; q++) g2 += s_red[q * 16 + tid];
        Gf[(size_t)n * D_OUT + tid] = g2;
    }
}

__global__ __launch_bounds__(256) void k_f1(
    const int* __restrict__ nbr_cnt, const u16* __restrict__ nbr_idx,
    const float* __restrict__ Gf, const int* __restrict__ flag,
    void* __restrict__ dout)
{
    int tid = threadIdx.x;
    int bf = *flag;
    int r = tid >> 4, o = tid & 15;
    int n = blockIdx.x * 16 + r;
    int cnt = nbr_cnt[n];
    const u16* idx = nbr_idx + (size_t)n * MAXN;
    float acc = 0.f;
    for (int t = 0; t < cnt; t++)
        acc += Gf[(size_t)idx[t] * D_OUT + o];
    acc = fmaxf(acc, 0.f);
    store_out(dout, bf, (size_t)OUT_OFF + (size_t)n * D_OUT + o, acc);
    store_out(dout, bf, (size_t)Z1_OFF  + (size_t)n * D_OUT + o, acc);
}

extern "C" void kernel_launch(void* const* d_in, const int* in_sizes, int n_in,
                              void* d_out, int out_size, void* d_ws, size_t ws_size,
                              hipStream_t stream) {
    const void* x    = d_in[0];
    const void* adj  = d_in[1];
    const void* C_a  = d_in[2];
    const void* W    = d_in[3];
    const void* av   = d_in[4];
    const void* Wgcn = d_in[5];

    char* wsp = (char*)d_ws;
    int*   flag = (int*)wsp;                   wsp += 256;
    float* Wh   = (float*)wsp;                 wsp += (size_t)N_NODES * H * 4;
    float* Wh1  = (float*)wsp;                 wsp += (size_t)N_NODES * 4;
    float* Wh2  = (float*)wsp;                 wsp += (size_t)N_NODES * 4;
    float* Gf   = (float*)wsp;                 wsp += (size_t)N_NODES * D_OUT * 4;
    int*   ncnt = (int*)wsp;                   wsp += (size_t)N_NODES * 4;
    u16*   nidx = (u16*)wsp;                   wsp += (size_t)N_NODES * MAXN * 2;
    float* a_f  = (float*)wsp;                 wsp += 2 * H * 4;
    float* Ca_f = (float*)wsp;                 wsp += (size_t)K_CL * H * 4;
    float* Wg_f = (float*)wsp;                 wsp += (size_t)H * D_OUT * 4;
    u16*   Wt   = (u16*)wsp;                   wsp += (size_t)H * D_IN * 2;

    hipMemsetAsync(flag, 0, sizeof(int), stream);
    k_detect <<<64, 256, 0, stream>>>((const u32*)adj, flag);
    k_prep   <<<546, 256, 0, stream>>>(av, C_a, Wgcn, W, flag, a_f, Ca_f, Wg_f, Wt);
    k_gemm_wh<<<2048, 256, 0, stream>>>(x, W, Wt, flag, Wh);
    k_wh12   <<<N_NODES / 4, 256, 0, stream>>>(Wh, a_f, Wh1, Wh2);
    k_gat_row<<<N_NODES, 256, 0, stream>>>(adj, flag, Wh, Wh1, Wh2, Ca_f, Wg_f,
                                           Gf, ncnt, nidx, d_out);
    k_f1     <<<N_NODES / 16, 256, 0, stream>>>(ncnt, nidx, Gf, flag, d_out);
}

// Round 4
// 480.387 us; speedup vs baseline: 1.3309x; 1.3309x over previous
//
#include <hip/hip_runtime.h>
#include <hip/hip_bf16.h>

#define N_NODES 8192
#define D_IN    512
#define H       256
#define D_OUT   16
#define K_CL    16
#define MAXN    96

// flat output element offsets (dtype-agnostic): output | Z_1 | Z_0 | score
#define OUT_OFF 0
#define Z1_OFF  131072
#define Z0_OFF  262144
#define SC_OFF  2359296

typedef unsigned int   u32;
typedef unsigned short u16;
typedef short s16x8 __attribute__((ext_vector_type(8)));   // bf16 MFMA A/B frag
typedef float f32x4 __attribute__((ext_vector_type(4)));   // MFMA C/D frag

__device__ __forceinline__ float load_in(const void* p, int bf, size_t idx) {
    if (bf) { u32 w = ((const u16*)p)[idx]; return __uint_as_float(w << 16); }
    return ((const float*)p)[idx];
}
__device__ __forceinline__ void store_out(void* p, int bf, size_t idx, float v) {
    if (bf) ((__hip_bfloat16*)p)[idx] = __float2bfloat16(v);
    else    ((float*)p)[idx] = v;
}
__device__ __forceinline__ u16 f2bf(float v) {
    return (u16)__hip_bfloat16_raw(__float2bfloat16(v)).x;
}
__device__ __forceinline__ float bf2f(u16 b) { return __uint_as_float(((u32)b) << 16); }

// bf16 {0,1} arrays contain u32 word 0x00003F80 (pair (1.0, 0.0));
// fp32 {0.0f,1.0f} arrays contain only 0x00000000 / 0x3F800000.
__global__ void k_detect(const u32* __restrict__ adjw, int* __restrict__ flag) {
    int t = blockIdx.x * 256 + threadIdx.x;
    int hit = 0;
    #pragma unroll 4
    for (int i = 0; i < 64; i++)
        if (adjw[(size_t)t + (size_t)i * 16384] == 0x00003F80u) hit = 1;
    if (hit) atomicOr(flag, 1);
}

// a/C_a/W_gcn -> f32; W -> transposed bf16 hi/lo splits Wht/Wlt [H][D_IN]
__global__ void k_prep(const void* av, const void* C_a, const void* Wgcn, const void* W,
                       const int* __restrict__ flag,
                       float* a_f, float* Ca_f, float* Wg_f,
                       u16* Wht, u16* Wlt) {
    int bf = *flag;
    int i = blockIdx.x * 256 + threadIdx.x;
    if (i < 512)        a_f[i]         = load_in(av,   bf, i);
    else if (i < 4608)  Ca_f[i - 512]  = load_in(C_a,  bf, i - 512);
    else if (i < 8704)  Wg_f[i - 4608] = load_in(Wgcn, bf, i - 4608);
    else if (i < 139776) {
        int j = i - 8704;                      // j = nn*512 + kk
        int nn = j >> 9, kk = j & 511;         // Wt[nn][kk] = W[kk][nn]
        size_t src = (size_t)kk * H + nn;
        if (bf) {
            Wht[j] = ((const u16*)W)[src];
            Wlt[j] = 0;
        } else {
            float w = ((const float*)W)[src];
            u16 hi = f2bf(w);
            Wht[j] = hi;
            Wlt[j] = f2bf(w - bf2f(hi));
        }
    }
}

// x -> bf16 hi/lo splits (row-major, same layout). bf16 input: hi=x, lo unused.
__global__ __launch_bounds__(256) void k_split(
    const void* __restrict__ xraw, const int* __restrict__ flag,
    u16* __restrict__ xhi, u16* __restrict__ xlo)
{
    int bf = *flag;
    size_t t = (size_t)blockIdx.x * 256 + threadIdx.x;   // 4 elems per thread
    if (bf) {
        uint2 v = ((const uint2*)xraw)[t];
        ((uint2*)xhi)[t] = v;
    } else {
        float4 v = ((const float4*)xraw)[t];
        u16 h[4], l[4];
        float vv[4] = {v.x, v.y, v.z, v.w};
        #pragma unroll
        for (int i = 0; i < 4; i++) {
            h[i] = f2bf(vv[i]);
            l[i] = f2bf(vv[i] - bf2f(h[i]));
        }
        ((uint2*)xhi)[t] = make_uint2((u32)h[0] | ((u32)h[1] << 16), (u32)h[2] | ((u32)h[3] << 16));
        ((uint2*)xlo)[t] = make_uint2((u32)l[0] | ((u32)l[1] << 16), (u32)l[2] | ((u32)l[3] << 16));
    }
}

// Wh = x @ W via MFMA 16x16x32_bf16. fp32 inputs: 3-term bf16 split (hi*hi + hi*lo + lo*hi).
// One block (16 waves) owns a 16-row stripe; wave = column tile -> x stripe fetched once.
__global__ __launch_bounds__(1024) void k_gemm_wh(
    const u16* __restrict__ xhi, const u16* __restrict__ xlo,
    const u16* __restrict__ Wht, const u16* __restrict__ Wlt,
    const int* __restrict__ flag, float* __restrict__ Wh)
{
    int bf = *flag;
    int tid = threadIdx.x, wave = tid >> 6, lane = tid & 63;
    int m0 = blockIdx.x * 16, n0 = wave * 16;
    int quad = lane >> 4, lr = lane & 15;

    size_t aoff = (size_t)(m0 + lr) * D_IN + quad * 8;
    size_t boff = (size_t)(n0 + lr) * D_IN + quad * 8;
    const u16* ah = xhi + aoff;
    const u16* bh = Wht + boff;
    f32x4 acc = {0.f, 0.f, 0.f, 0.f};

    if (bf) {
        #pragma unroll
        for (int k0 = 0; k0 < D_IN; k0 += 32) {
            s16x8 a = *(const s16x8*)(ah + k0);
            s16x8 b = *(const s16x8*)(bh + k0);
            acc = __builtin_amdgcn_mfma_f32_16x16x32_bf16(a, b, acc, 0, 0, 0);
        }
    } else {
        const u16* al = xlo + aoff;
        const u16* bl = Wlt + boff;
        #pragma unroll
        for (int k0 = 0; k0 < D_IN; k0 += 32) {
            s16x8 a  = *(const s16x8*)(ah + k0);
            s16x8 b  = *(const s16x8*)(bh + k0);
            s16x8 a2 = *(const s16x8*)(al + k0);
            s16x8 b2 = *(const s16x8*)(bl + k0);
            acc = __builtin_amdgcn_mfma_f32_16x16x32_bf16(a,  b,  acc, 0, 0, 0);
            acc = __builtin_amdgcn_mfma_f32_16x16x32_bf16(a,  b2, acc, 0, 0, 0);
            acc = __builtin_amdgcn_mfma_f32_16x16x32_bf16(a2, b,  acc, 0, 0, 0);
        }
    }
    // C/D layout: col = lane&15, row = (lane>>4)*4 + i
    float* cp = Wh + (size_t)(m0 + quad * 4) * H + n0 + lr;
    #pragma unroll
    for (int i = 0; i < 4; i++) cp[(size_t)i * H] = acc[i];
}

__global__ __launch_bounds__(256) void k_wh12(
    const float* __restrict__ Wh, const float* __restrict__ a_f,
    float* __restrict__ Wh1, float* __restrict__ Wh2)
{
    int tid = threadIdx.x;
    int wave = tid >> 6, lane = tid & 63;
    int n = blockIdx.x * 4 + wave;
    float4 v  = *(const float4*)(Wh + (size_t)n * H + lane * 4);
    float4 a1 = *(const float4*)(a_f + lane * 4);
    float4 a2 = *(const float4*)(a_f + H + lane * 4);
    float s1 = v.x*a1.x + v.y*a1.y + v.z*a1.z + v.w*a1.w;
    float s2 = v.x*a2.x + v.y*a2.y + v.z*a2.z + v.w*a2.w;
    #pragma unroll
    for (int off = 32; off; off >>= 1) {
        s1 += __shfl_xor(s1, off);
        s2 += __shfl_xor(s2, off);
    }
    if (lane == 0) { Wh1[n] = s1; Wh2[n] = s2; }
}

__global__ __launch_bounds__(256) void k_gat_row(
    const void* __restrict__ adjraw, const int* __restrict__ flag,
    const float* __restrict__ Wh,
    const float* __restrict__ Wh1, const float* __restrict__ Wh2,
    const float* __restrict__ Ca_f, const float* __restrict__ Wg_f,
    float* __restrict__ Gf,
    int* __restrict__ nbr_cnt, u16* __restrict__ nbr_idx,
    void* __restrict__ dout)
{
    const int n = blockIdx.x;
    const int tid = threadIdx.x;
    const int wave = tid >> 6, lane = tid & 63;
    const int bf = *flag;
    __shared__ int   s_cnt;
    __shared__ int   s_idx[MAXN];
    __shared__ float s_att[MAXN];
    __shared__ float s_z[H];
    __shared__ float s_g[H];
    __shared__ float s_red[256];
    __shared__ float s_sc[16];

    if (tid == 0) s_cnt = 0;
    __syncthreads();

    if (bf) {
        const u16* arow = (const u16*)adjraw + (size_t)n * N_NODES;
        #pragma unroll
        for (int it = 0; it < 4; it++) {
            int base = it * 2048 + tid * 8;
            uint4 raw = *(const uint4*)(arow + base);
            u32 rw[4] = {raw.x, raw.y, raw.z, raw.w};
            #pragma unroll
            for (int q = 0; q < 4; q++) {
                #pragma unroll
                for (int hh = 0; hh < 2; hh++) {
                    u32 u = (rw[q] >> (16 * hh)) & 0xFFFFu;
                    if (__uint_as_float(u << 16) > 0.f) {
                        int p = atomicAdd(&s_cnt, 1);
                        if (p < MAXN) s_idx[p] = base + q * 2 + hh;
                    }
                }
            }
        }
    } else {
        const float* arow = (const float*)adjraw + (size_t)n * N_NODES;
        #pragma unroll
        for (int it = 0; it < 8; it++) {
            int base = it * 1024 + tid * 4;
            float4 v = *(const float4*)(arow + base);
            float vv[4] = {v.x, v.y, v.z, v.w};
            #pragma unroll
            for (int q = 0; q < 4; q++) {
                if (vv[q] > 0.f) {
                    int p = atomicAdd(&s_cnt, 1);
                    if (p < MAXN) s_idx[p] = base + q;
                }
            }
        }
    }
    __syncthreads();
    const int cnt = min(s_cnt, MAXN);
    if (tid == 0) nbr_cnt[n] = cnt;
    if (tid < cnt) nbr_idx[(size_t)n * MAXN + tid] = (u16)s_idx[tid];

    // softmax over neighbors, single wave (cnt <= 96), shuffle butterflies
    if (wave == 0) {
        int t1 = lane, t2 = 64 + lane;
        float whn = Wh1[n];
        float e1 = -3e38f, e2 = -3e38f;
        if (t1 < cnt) { float v = whn + Wh2[s_idx[t1]]; e1 = v > 0.f ? v : 0.2f * v; }
        if (t2 < cnt) { float v = whn + Wh2[s_idx[t2]]; e2 = v > 0.f ? v : 0.2f * v; }
        float m = fmaxf(e1, e2);
        #pragma unroll
        for (int off = 32; off; off >>= 1) m = fmaxf(m, __shfl_xor(m, off));
        float x1 = (t1 < cnt) ? expf(e1 - m) : 0.f;
        float x2 = (t2 < cnt) ? expf(e2 - m) : 0.f;
        float s = x1 + x2;
        #pragma unroll
        for (int off = 32; off; off >>= 1) s += __shfl_xor(s, off);
        float inv = 1.f / s;
        if (t1 < cnt) s_att[t1] = x1 * inv;
        if (t2 < cnt) s_att[t2] = x2 * inv;
    }
    __syncthreads();

    // Z0[n][h] = sum_j att_j * Wh[j][h]
    float acc = 0.f;
    for (int t = 0; t < cnt; t++)
        acc += s_att[t] * Wh[(size_t)s_idx[t] * H + tid];
    s_z[tid] = acc;
    store_out(dout, bf, (size_t)Z0_OFF + (size_t)n * H + tid, acc);
    s_g[tid] = acc > 0.f ? acc : expf(acc) - 1.f;
    __syncthreads();

    {
        int k = tid & 15, hb = (tid >> 4) * 16;
        float p = 0.f;
        #pragma unroll
        for (int i = 0; i < 16; i++) {
            float d = s_z[hb + i] - Ca_f[(size_t)k * H + hb + i];
            p += d * d;
        }
        s_red[tid] = p;
    }
    __syncthreads();
    if (tid < 16) {
        float d2 = 0.f;
        #pragma unroll
        for (int q = 0; q < 16; q++) d2 += s_red[q * 16 + tid];
        s_sc[tid] = expf(-sqrtf(d2)) + 1e-10f;
    }
    __syncthreads();
    if (tid < 16) {
        float tot = 0.f;
        #pragma unroll
        for (int q = 0; q < 16; q++) tot += s_sc[q];
        store_out(dout, bf, (size_t)SC_OFF + (size_t)n * K_CL + tid, s_sc[tid] / tot);
    }
    {
        int o = tid & 15, hb = (tid >> 4) * 16;
        float p = 0.f;
        #pragma unroll
        for (int i = 0; i < 16; i++)
            p += s_g[hb + i] * Wg_f[(size_t)(hb + i) * D_OUT + o];
        s_red[tid] = p;
    }
    __syncthreads();
    if (tid < 16) {
        float g2 = 0.f;
        #pragma unroll
        for (int q = 0; q < 16; q++) g2 += s_red[q * 16 + tid];
        Gf[(size_t)n * D_OUT + tid] = g2;
    }
}

__global__ __launch_bounds__(256) void k_f1(
    const int* __restrict__ nbr_cnt, const u16* __restrict__ nbr_idx,
    const float* __restrict__ Gf, const int* __restrict__ flag,
    void* __restrict__ dout)
{
    int tid = threadIdx.x;
    int bf = *flag;
    int r = tid >> 4, o = tid & 15;
    int n = blockIdx.x * 16 + r;
    int cnt = nbr_cnt[n];
    const u16* idx = nbr_idx + (size_t)n * MAXN;
    float acc = 0.f;
    for (int t = 0; t < cnt; t++)
        acc += Gf[(size_t)idx[t] * D_OUT + o];
    acc = fmaxf(acc, 0.f);
    store_out(dout, bf, (size_t)OUT_OFF + (size_t)n * D_OUT + o, acc);
    store_out(dout, bf, (size_t)Z1_OFF  + (size_t)n * D_OUT + o, acc);
}

extern "C" void kernel_launch(void* const* d_in, const int* in_sizes, int n_in,
                              void* d_out, int out_size, void* d_ws, size_t ws_size,
                              hipStream_t stream) {
    const void* x    = d_in[0];
    const void* adj  = d_in[1];
    const void* C_a  = d_in[2];
    const void* W    = d_in[3];
    const void* av   = d_in[4];
    const void* Wgcn = d_in[5];

    char* wsp = (char*)d_ws;
    int*   flag = (int*)wsp;                   wsp += 256;
    float* Wh   = (float*)wsp;                 wsp += (size_t)N_NODES * H * 4;
    float* Wh1  = (float*)wsp;                 wsp += (size_t)N_NODES * 4;
    float* Wh2  = (float*)wsp;                 wsp += (size_t)N_NODES * 4;
    float* Gf   = (float*)wsp;                 wsp += (size_t)N_NODES * D_OUT * 4;
    int*   ncnt = (int*)wsp;                   wsp += (size_t)N_NODES * 4;
    u16*   nidx = (u16*)wsp;                   wsp += (size_t)N_NODES * MAXN * 2;
    float* a_f  = (float*)wsp;                 wsp += 2 * H * 4;
    float* Ca_f = (float*)wsp;                 wsp += (size_t)K_CL * H * 4;
    float* Wg_f = (float*)wsp;                 wsp += (size_t)H * D_OUT * 4;
    u16*   Wht  = (u16*)wsp;                   wsp += (size_t)H * D_IN * 2;
    u16*   Wlt  = (u16*)wsp;                   wsp += (size_t)H * D_IN * 2;
    u16*   xhi  = (u16*)wsp;                   wsp += (size_t)N_NODES * D_IN * 2;
    u16*   xlo  = (u16*)wsp;                   wsp += (size_t)N_NODES * D_IN * 2;

    hipMemsetAsync(flag, 0, sizeof(int), stream);
    k_detect <<<64, 256, 0, stream>>>((const u32*)adj, flag);
    k_prep   <<<546, 256, 0, stream>>>(av, C_a, Wgcn, W, flag, a_f, Ca_f, Wg_f, Wht, Wlt);
    k_split  <<<4096, 256, 0, stream>>>(x, flag, xhi, xlo);
    k_gemm_wh<<<512, 1024, 0, stream>>>(xhi, xlo, Wht, Wlt, flag, Wh);
    k_wh12   <<<N_NODES / 4, 256, 0, stream>>>(Wh, a_f, Wh1, Wh2);
    k_gat_row<<<N_NODES, 256, 0, stream>>>(adj, flag, Wh, Wh1, Wh2, Ca_f, Wg_f,
                                           Gf, ncnt, nidx, d_out);
    k_f1     <<<N_NODES / 16, 256, 0, stream>>>(ncnt, nidx, Gf, flag, d_out);
}

// Round 5
// 475.574 us; speedup vs baseline: 1.3444x; 1.0101x over previous
//
#include <hip/hip_runtime.h>
#include <hip/hip_bf16.h>

#define N_NODES 8192
#define D_IN    512
#define H       256
#define D_OUT   16
#define K_CL    16
#define MAXN    96

// flat output element offsets (dtype-agnostic): output | Z_1 | Z_0 | score
#define OUT_OFF 0
#define Z1_OFF  131072
#define Z0_OFF  262144
#define SC_OFF  2359296

typedef unsigned int   u32;
typedef unsigned short u16;
typedef short s16x8 __attribute__((ext_vector_type(8)));   // bf16 MFMA A/B frag
typedef float f32x4 __attribute__((ext_vector_type(4)));   // MFMA C/D frag

__device__ __forceinline__ float load_in(const void* p, int bf, size_t idx) {
    if (bf) { u32 w = ((const u16*)p)[idx]; return __uint_as_float(w << 16); }
    return ((const float*)p)[idx];
}
__device__ __forceinline__ void store_out(void* p, int bf, size_t idx, float v) {
    if (bf) ((__hip_bfloat16*)p)[idx] = __float2bfloat16(v);
    else    ((float*)p)[idx] = v;
}
__device__ __forceinline__ u16 f2bf(float v) {
    return (u16)__hip_bfloat16_raw(__float2bfloat16(v)).x;
}
__device__ __forceinline__ float bf2f(u16 b) { return __uint_as_float(((u32)b) << 16); }

// bf16 {0,1} arrays contain u32 word 0x00003F80 (pair (1.0, 0.0));
// fp32 {0.0f,1.0f} arrays contain only 0x00000000 / 0x3F800000.
__global__ void k_detect(const u32* __restrict__ adjw, int* __restrict__ flag) {
    int t = blockIdx.x * 256 + threadIdx.x;
    int hit = 0;
    #pragma unroll 4
    for (int i = 0; i < 64; i++)
        if (adjw[(size_t)t + (size_t)i * 16384] == 0x00003F80u) hit = 1;
    if (hit) atomicOr(flag, 1);
}

// a/C_a/W_gcn -> f32; W -> transposed bf16 hi/lo splits Wht/Wlt [H][D_IN]
__global__ void k_prep(const void* av, const void* C_a, const void* Wgcn, const void* W,
                       const int* __restrict__ flag,
                       float* a_f, float* Ca_f, float* Wg_f,
                       u16* Wht, u16* Wlt) {
    int bf = *flag;
    int i = blockIdx.x * 256 + threadIdx.x;
    if (i < 512)        a_f[i]         = load_in(av,   bf, i);
    else if (i < 4608)  Ca_f[i - 512]  = load_in(C_a,  bf, i - 512);
    else if (i < 8704)  Wg_f[i - 4608] = load_in(Wgcn, bf, i - 4608);
    else if (i < 139776) {
        int j = i - 8704;                      // j = nn*512 + kk
        int nn = j >> 9, kk = j & 511;         // Wt[nn][kk] = W[kk][nn]
        size_t src = (size_t)kk * H + nn;
        if (bf) {
            Wht[j] = ((const u16*)W)[src];
            Wlt[j] = 0;
        } else {
            float w = ((const float*)W)[src];
            u16 hi = f2bf(w);
            Wht[j] = hi;
            Wlt[j] = f2bf(w - bf2f(hi));
        }
    }
}

// Wh = x @ W via MFMA 16x16x32_bf16; fp32 x converted to bf16 hi/lo IN-REGISTER
// (3-term Ootomo split: hi*hi + hi*lo + lo*hi, rel err ~2^-16).
// One block (16 waves) owns a 16-row stripe; wave = column tile -> x stripe fetched once.
__global__ __launch_bounds__(1024) void k_gemm_wh(
    const void* __restrict__ xraw,
    const u16* __restrict__ Wht, const u16* __restrict__ Wlt,
    const int* __restrict__ flag, float* __restrict__ Wh)
{
    int bf = *flag;
    int tid = threadIdx.x, wave = tid >> 6, lane = tid & 63;
    int m0 = blockIdx.x * 16, n0 = wave * 16;
    int quad = lane >> 4, lr = lane & 15;

    size_t boff = (size_t)(n0 + lr) * D_IN + quad * 8;
    const u16* bh = Wht + boff;
    f32x4 acc = {0.f, 0.f, 0.f, 0.f};

    if (bf) {
        const u16* ah = (const u16*)xraw + (size_t)(m0 + lr) * D_IN + quad * 8;
        #pragma unroll
        for (int k0 = 0; k0 < D_IN; k0 += 32) {
            s16x8 a = *(const s16x8*)(ah + k0);
            s16x8 b = *(const s16x8*)(bh + k0);
            acc = __builtin_amdgcn_mfma_f32_16x16x32_bf16(a, b, acc, 0, 0, 0);
        }
    } else {
        const float* af = (const float*)xraw + (size_t)(m0 + lr) * D_IN + quad * 8;
        const u16* bl = Wlt + boff;
        #pragma unroll
        for (int k0 = 0; k0 < D_IN; k0 += 32) {
            float4 f0 = *(const float4*)(af + k0);
            float4 f1 = *(const float4*)(af + k0 + 4);
            float v[8] = {f0.x, f0.y, f0.z, f0.w, f1.x, f1.y, f1.z, f1.w};
            s16x8 ahi, alo;
            #pragma unroll
            for (int i = 0; i < 8; i++) {
                u16 h = f2bf(v[i]);
                ahi[i] = (short)h;
                alo[i] = (short)f2bf(v[i] - bf2f(h));
            }
            s16x8 b  = *(const s16x8*)(bh + k0);
            s16x8 b2 = *(const s16x8*)(bl + k0);
            acc = __builtin_amdgcn_mfma_f32_16x16x32_bf16(ahi, b,  acc, 0, 0, 0);
            acc = __builtin_amdgcn_mfma_f32_16x16x32_bf16(ahi, b2, acc, 0, 0, 0);
            acc = __builtin_amdgcn_mfma_f32_16x16x32_bf16(alo, b,  acc, 0, 0, 0);
        }
    }
    // C/D layout: col = lane&15, row = (lane>>4)*4 + i
    float* cp = Wh + (size_t)(m0 + quad * 4) * H + n0 + lr;
    #pragma unroll
    for (int i = 0; i < 4; i++) cp[(size_t)i * H] = acc[i];
}

__global__ __launch_bounds__(256) void k_wh12(
    const float* __restrict__ Wh, const float* __restrict__ a_f,
    float* __restrict__ Wh1, float* __restrict__ Wh2)
{
    int tid = threadIdx.x;
    int wave = tid >> 6, lane = tid & 63;
    int n = blockIdx.x * 4 + wave;
    float4 v  = *(const float4*)(Wh + (size_t)n * H + lane * 4);
    float4 a1 = *(const float4*)(a_f + lane * 4);
    float4 a2 = *(const float4*)(a_f + H + lane * 4);
    float s1 = v.x*a1.x + v.y*a1.y + v.z*a1.z + v.w*a1.w;
    float s2 = v.x*a2.x + v.y*a2.y + v.z*a2.z + v.w*a2.w;
    #pragma unroll
    for (int off = 32; off; off >>= 1) {
        s1 += __shfl_xor(s1, off);
        s2 += __shfl_xor(s2, off);
    }
    if (lane == 0) { Wh1[n] = s1; Wh2[n] = s2; }
}

__global__ __launch_bounds__(256) void k_gat_row(
    const void* __restrict__ adjraw, const int* __restrict__ flag,
    const float* __restrict__ Wh,
    const float* __restrict__ Wh1, const float* __restrict__ Wh2,
    const float* __restrict__ Ca_f, const float* __restrict__ Wg_f,
    float* __restrict__ Gf,
    int* __restrict__ nbr_cnt, u16* __restrict__ nbr_idx,
    void* __restrict__ dout)
{
    const int n = blockIdx.x;
    const int tid = threadIdx.x;
    const int wave = tid >> 6, lane = tid & 63;
    const int bf = *flag;
    __shared__ int   s_cnt;
    __shared__ int   s_idx[MAXN];
    __shared__ float s_att[MAXN];
    __shared__ float s_z[H];
    __shared__ float s_g[H];
    __shared__ float s_red[256];
    __shared__ float s_sc[16];

    if (tid == 0) s_cnt = 0;
    __syncthreads();

    if (bf) {
        const u16* arow = (const u16*)adjraw + (size_t)n * N_NODES;
        #pragma unroll
        for (int it = 0; it < 4; it++) {
            int base = it * 2048 + tid * 8;
            uint4 raw = *(const uint4*)(arow + base);
            u32 rw[4] = {raw.x, raw.y, raw.z, raw.w};
            #pragma unroll
            for (int q = 0; q < 4; q++) {
                #pragma unroll
                for (int hh = 0; hh < 2; hh++) {
                    u32 u = (rw[q] >> (16 * hh)) & 0xFFFFu;
                    if (__uint_as_float(u << 16) > 0.f) {
                        int p = atomicAdd(&s_cnt, 1);
                        if (p < MAXN) s_idx[p] = base + q * 2 + hh;
                    }
                }
            }
        }
    } else {
        const float* arow = (const float*)adjraw + (size_t)n * N_NODES;
        #pragma unroll
        for (int it = 0; it < 8; it++) {
            int base = it * 1024 + tid * 4;
            float4 v = *(const float4*)(arow + base);
            float vv[4] = {v.x, v.y, v.z, v.w};
            #pragma unroll
            for (int q = 0; q < 4; q++) {
                if (vv[q] > 0.f) {
                    int p = atomicAdd(&s_cnt, 1);
                    if (p < MAXN) s_idx[p] = base + q;
                }
            }
        }
    }
    __syncthreads();
    const int cnt = min(s_cnt, MAXN);
    if (tid == 0) nbr_cnt[n] = cnt;
    if (tid < cnt) nbr_idx[(size_t)n * MAXN + tid] = (u16)s_idx[tid];

    // softmax over neighbors, single wave (cnt <= 96), shuffle butterflies
    if (wave == 0) {
        int t1 = lane, t2 = 64 + lane;
        float whn = Wh1[n];
        float e1 = -3e38f, e2 = -3e38f;
        if (t1 < cnt) { float v = whn + Wh2[s_idx[t1]]; e1 = v > 0.f ? v : 0.2f * v; }
        if (t2 < cnt) { float v = whn + Wh2[s_idx[t2]]; e2 = v > 0.f ? v : 0.2f * v; }
        float m = fmaxf(e1, e2);
        #pragma unroll
        for (int off = 32; off; off >>= 1) m = fmaxf(m, __shfl_xor(m, off));
        float x1 = (t1 < cnt) ? expf(e1 - m) : 0.f;
        float x2 = (t2 < cnt) ? expf(e2 - m) : 0.f;
        float s = x1 + x2;
        #pragma unroll
        for (int off = 32; off; off >>= 1) s += __shfl_xor(s, off);
        float inv = 1.f / s;
        if (t1 < cnt) s_att[t1] = x1 * inv;
        if (t2 < cnt) s_att[t2] = x2 * inv;
    }
    __syncthreads();

    // Z0[n][h] = sum_j att_j * Wh[j][h]
    float acc = 0.f;
    for (int t = 0; t < cnt; t++)
        acc += s_att[t] * Wh[(size_t)s_idx[t] * H + tid];
    s_z[tid] = acc;
    store_out(dout, bf, (size_t)Z0_OFF + (size_t)n * H + tid, acc);
    s_g[tid] = acc > 0.f ? acc : expf(acc) - 1.f;
    __syncthreads();

    {
        int k = tid & 15, hb = (tid >> 4) * 16;
        float p = 0.f;
        #pragma unroll
        for (int i = 0; i < 16; i++) {
            float d = s_z[hb + i] - Ca_f[(size_t)k * H + hb + i];
            p += d * d;
        }
        s_red[tid] = p;
    }
    __syncthreads();
    if (tid < 16) {
        float d2 = 0.f;
        #pragma unroll
        for (int q = 0; q < 16; q++) d2 += s_red[q * 16 + tid];
        s_sc[tid] = expf(-sqrtf(d2)) + 1e-10f;
    }
    __syncthreads();
    if (tid < 16) {
        float tot = 0.f;
        #pragma unroll
        for (int q = 0; q < 16; q++) tot += s_sc[q];
        store_out(dout, bf, (size_t)SC_OFF + (size_t)n * K_CL + tid, s_sc[tid] / tot);
    }
    {
        int o = tid & 15, hb = (tid >> 4) * 16;
        float p = 0.f;
        #pragma unroll
        for (int i = 0; i < 16; i++)
            p += s_g[hb + i] * Wg_f[(size_t)(hb + i) * D_OUT + o];
        s_red[tid] = p;
    }
    __syncthreads();
    if (tid < 16) {
        float g2 = 0.f;
        #pragma unroll
        for (int q = 0; q < 16; q++) g2 += s_red[q * 16 + tid];
        Gf[(size_t)n * D_OUT + tid] = g2;
    }
}

__global__ __launch_bounds__(256) void k_f1(
    const int* __restrict__ nbr_cnt, const u16* __restrict__ nbr_idx,
    const float* __restrict__ Gf, const int* __restrict__ flag,
    void* __restrict__ dout)
{
    int tid = threadIdx.x;
    int bf = *flag;
    int r = tid >> 4, o = tid & 15;
    int n = blockIdx.x * 16 + r;
    int cnt = nbr_cnt[n];
    const u16* idx = nbr_idx + (size_t)n * MAXN;
    float acc = 0.f;
    for (int t = 0; t < cnt; t++)
        acc += Gf[(size_t)idx[t] * D_OUT + o];
    acc = fmaxf(acc, 0.f);
    store_out(dout, bf, (size_t)OUT_OFF + (size_t)n * D_OUT + o, acc);
    store_out(dout, bf, (size_t)Z1_OFF  + (size_t)n * D_OUT + o, acc);
}

extern "C" void kernel_launch(void* const* d_in, const int* in_sizes, int n_in,
                              void* d_out, int out_size, void* d_ws, size_t ws_size,
                              hipStream_t stream) {
    const void* x    = d_in[0];
    const void* adj  = d_in[1];
    const void* C_a  = d_in[2];
    const void* W    = d_in[3];
    const void* av   = d_in[4];
    const void* Wgcn = d_in[5];

    char* wsp = (char*)d_ws;
    int*   flag = (int*)wsp;                   wsp += 256;
    float* Wh   = (float*)wsp;                 wsp += (size_t)N_NODES * H * 4;
    float* Wh1  = (float*)wsp;                 wsp += (size_t)N_NODES * 4;
    float* Wh2  = (float*)wsp;                 wsp += (size_t)N_NODES * 4;
    float* Gf   = (float*)wsp;                 wsp += (size_t)N_NODES * D_OUT * 4;
    int*   ncnt = (int*)wsp;                   wsp += (size_t)N_NODES * 4;
    u16*   nidx = (u16*)wsp;                   wsp += (size_t)N_NODES * MAXN * 2;
    float* a_f  = (float*)wsp;                 wsp += 2 * H * 4;
    float* Ca_f = (float*)wsp;                 wsp += (size_t)K_CL * H * 4;
    float* Wg_f = (float*)wsp;                 wsp += (size_t)H * D_OUT * 4;
    u16*   Wht  = (u16*)wsp;                   wsp += (size_t)H * D_IN * 2;
    u16*   Wlt  = (u16*)wsp;                   wsp += (size_t)H * D_IN * 2;

    hipMemsetAsync(flag, 0, sizeof(int), stream);
    k_detect <<<64, 256, 0, stream>>>((const u32*)adj, flag);
    k_prep   <<<546, 256, 0, stream>>>(av, C_a, Wgcn, W, flag, a_f, Ca_f, Wg_f, Wht, Wlt);
    k_gemm_wh<<<512, 1024, 0, stream>>>(x, Wht, Wlt, flag, Wh);
    k_wh12   <<<N_NODES / 4, 256, 0, stream>>>(Wh, a_f, Wh1, Wh2);
    k_gat_row<<<N_NODES, 256, 0, stream>>>(adj, flag, Wh, Wh1, Wh2, Ca_f, Wg_f,
                                           Gf, ncnt, nidx, d_out);
    k_f1     <<<N_NODES / 16, 256, 0, stream>>>(ncnt, nidx, Gf, flag, d_out);
}